// Round 3
// baseline (73.404 us; speedup 1.0000x reference)
//
#include <hip/hip_runtime.h>

#define N_TYPES 4
#define N_DESC  8
#define K_MAX   8
#define M_NBR   20
#define NCOMP   20                    // 1 (l0) + 3 (l1) + 6 (l2) + 10 (l3)
#define ATOMS   16
#define BLOCK   256
#define P1_ITEMS (ATOMS * M_NBR)      // 320

constexpr float R_C = 5.0f;
constexpr float SQ2 = 1.41421356237309515f;
constexpr float SQ3 = 1.73205080756887729f;
constexpr float SQ6 = 2.44948974968163702f;

// q[i][d][l] = sum_{j<k} g_ijd g_ikd P_l(cos th_jk)
//            = 0.5*scale_l*sum_{c in l} (sum_j g_jd F_c(u_j))^2 - 0.5*sum_j g_jd^2
// (Legendre addition theorem via traceless symmetric tensors; scale={1,1,3/2,5/2}).
// Phase 1: thread<->(atom,nbr): gather, Chebyshev, F_c(u), and g_d for ALL d inline.
// Phase 2: thread<->(atom,d): 20x20 register contraction, direct coalesced store.
__global__ __launch_bounds__(BLOCK) void AngularDescriptor_kernel(
    const int*   __restrict__ types,
    const float* __restrict__ pos,
    const int*   __restrict__ nbr,
    const float* __restrict__ c_table,
    float*       __restrict__ out,
    int N)
{
    __shared__ float sF[ATOMS][M_NBR][NCOMP];   // [a][m][c]  (rows 16B-aligned: 20f)
    __shared__ float sg[ATOMS][N_DESC][M_NBR];  // [a][d][m]  (rows 16B-aligned: 20f)

    const int t     = threadIdx.x;
    const int atom0 = blockIdx.x * ATOMS;

    // ---------------- phase 1: per-(atom, neighbor) ----------------
    for (int e = t; e < P1_ITEMS; e += BLOCK) {
        const int a    = e / M_NBR;
        const int m    = e - a * M_NBR;
        const int atom = atom0 + a;
        if (atom < N) {
            const int j  = nbr[atom * M_NBR + m];
            const int ti = types[atom];
            const int tj = types[j];
            const float dx = pos[j * 3 + 0] - pos[atom * 3 + 0];
            const float dy = pos[j * 3 + 1] - pos[atom * 3 + 1];
            const float dz = pos[j * 3 + 2] - pos[atom * 3 + 2];
            const float r2   = dx * dx + dy * dy + dz * dz;
            const float rinv = __builtin_amdgcn_rsqf(r2);
            const float r    = r2 * rinv;

            // Chebyshev basis * 0.5*fc   (v_cos takes revolutions: pi*r/rc -> r/(2rc))
            const float fc  = (r < R_C)
                ? (0.5f * __builtin_amdgcn_cosf(r * (0.5f / R_C)) + 0.5f) : 0.0f;
            const float hfc = 0.5f * fc;
            const float u   = r * (1.0f / R_C) - 1.0f;
            const float x   = 2.0f * u * u - 1.0f;
            float ch[K_MAX];
            ch[0] = 2.0f * hfc;
            ch[1] = (x + 1.0f) * hfc;
            float tkm2 = 1.0f, tkm1 = x;
            #pragma unroll
            for (int k = 2; k < K_MAX; ++k) {
                const float tk = 2.0f * x * tkm1 - tkm2;
                ch[k] = (tk + 1.0f) * hfc;
                tkm2 = tkm1; tkm1 = tk;
            }

            // g_d for all 8 descriptors: c row is 256 contiguous bytes (L1-hot 4KB table)
            const float* crow = c_table + (ti * N_TYPES + tj) * (N_DESC * K_MAX);
            float g[N_DESC];
            #pragma unroll
            for (int d = 0; d < N_DESC; ++d) {
                const float4 c0 = ((const float4*)crow)[2 * d + 0];
                const float4 c1 = ((const float4*)crow)[2 * d + 1];
                g[d] = c0.x * ch[0] + c0.y * ch[1] + c0.z * ch[2] + c0.w * ch[3]
                     + c1.x * ch[4] + c1.y * ch[5] + c1.z * ch[6] + c1.w * ch[7];
            }
            // d-rotated store order: simultaneous lanes (a,m) hit distinct banks
            #pragma unroll
            for (int dd = 0; dd < N_DESC; ++dd) {
                const int d = (dd + a) & 7;
                sg[a][d][m] = g[d];
            }

            // unit vector + tensor features
            const float ux = dx * rinv, uy = dy * rinv, uz = dz * rinv;
            const float x2 = ux * ux, y2 = uy * uy, z2 = uz * uz;
            float F[NCOMP];
            F[0]  = 1.0f;                       // l=0
            F[1]  = ux;  F[2] = uy;  F[3] = uz; // l=1
            F[4]  = x2 - (1.0f / 3.0f);         // l=2 (scale 3/2)
            F[5]  = y2 - (1.0f / 3.0f);
            F[6]  = z2 - (1.0f / 3.0f);
            F[7]  = SQ2 * ux * uy;
            F[8]  = SQ2 * ux * uz;
            F[9]  = SQ2 * uy * uz;
            F[10] = ux * (x2 - 0.6f);           // l=3 (scale 5/2)
            F[11] = uy * (y2 - 0.6f);
            F[12] = uz * (z2 - 0.6f);
            F[13] = SQ3 * uy * (x2 - 0.2f);
            F[14] = SQ3 * uz * (x2 - 0.2f);
            F[15] = SQ3 * ux * (y2 - 0.2f);
            F[16] = SQ3 * uz * (y2 - 0.2f);
            F[17] = SQ3 * ux * (z2 - 0.2f);
            F[18] = SQ3 * uy * (z2 - 0.2f);
            F[19] = SQ6 * ux * uy * uz;
            // chunk-rotated b128 stores (addresses unchanged; order kills conflicts)
            float4* frow = (float4*)&sF[a][m][0];
            const int mr = m % 5;
            #pragma unroll
            for (int ss = 0; ss < 5; ++ss) {
                int cc = ss + mr; cc = (cc >= 5) ? cc - 5 : cc;
                frow[cc] = make_float4(F[4*cc+0], F[4*cc+1], F[4*cc+2], F[4*cc+3]);
            }
        }
    }
    __syncthreads();

    // ---------------- phase 2: per-(atom, d) ----------------
    if (t < ATOMS * N_DESC) {
        const int a    = t >> 3;
        const int d    = t & 7;
        const int atom = atom0 + a;
        if (atom < N) {
            float g[M_NBR];
            const float4* gr = (const float4*)&sg[a][d][0];
            #pragma unroll
            for (int i = 0; i < 5; ++i) {
                const float4 v = gr[i];
                g[4*i+0] = v.x; g[4*i+1] = v.y; g[4*i+2] = v.z; g[4*i+3] = v.w;
            }
            float G2 = 0.f;
            #pragma unroll
            for (int m = 0; m < M_NBR; ++m) G2 = fmaf(g[m], g[m], G2);

            float acc[NCOMP];
            #pragma unroll
            for (int c = 0; c < NCOMP; ++c) acc[c] = 0.f;
            #pragma unroll
            for (int m = 0; m < M_NBR; ++m) {
                const float4* Fr = (const float4*)&sF[a][m][0];
                const float gm = g[m];
                #pragma unroll
                for (int i = 0; i < 5; ++i) {
                    const float4 f = Fr[i];
                    acc[4*i+0] = fmaf(gm, f.x, acc[4*i+0]);
                    acc[4*i+1] = fmaf(gm, f.y, acc[4*i+1]);
                    acc[4*i+2] = fmaf(gm, f.z, acc[4*i+2]);
                    acc[4*i+3] = fmaf(gm, f.w, acc[4*i+3]);
                }
            }
            float p1 = acc[1]*acc[1] + acc[2]*acc[2] + acc[3]*acc[3];
            float p2 = 0.f, p3 = 0.f;
            #pragma unroll
            for (int c = 4; c < 10; ++c)  p2 = fmaf(acc[c], acc[c], p2);
            #pragma unroll
            for (int c = 10; c < 20; ++c) p3 = fmaf(acc[c], acc[c], p3);
            const float hG2 = 0.5f * G2;
            ((float4*)out)[atom * N_DESC + d] = make_float4(
                0.5f  * acc[0] * acc[0] - hG2,
                0.5f  * p1               - hG2,
                0.75f * p2               - hG2,
                1.25f * p3               - hG2);
        }
    }
}

extern "C" void kernel_launch(void* const* d_in, const int* in_sizes, int n_in,
                              void* d_out, int out_size, void* d_ws, size_t ws_size,
                              hipStream_t stream) {
    const int*   types   = (const int*)  d_in[0];
    const float* pos     = (const float*)d_in[1];
    const int*   nbr     = (const int*)  d_in[2];
    const float* c_table = (const float*)d_in[3];
    float*       out     = (float*)      d_out;

    const int N = in_sizes[0];
    const int grid = (N + ATOMS - 1) / ATOMS;   // 625 blocks for N=10000
    AngularDescriptor_kernel<<<grid, BLOCK, 0, stream>>>(types, pos, nbr, c_table, out, N);
}

// Round 4
// 66.039 us; speedup vs baseline: 1.1115x; 1.1115x over previous
//
#include <hip/hip_runtime.h>

#define N_TYPES 4
#define N_DESC  8
#define K_MAX   8
#define M_NBR   20
#define NCOMP   20              // 1 (l0) + 3 (l1) + 6 (l2) + 10 (l3)
#define APB     2               // atoms per (single-wave) block
#define ROWP    28              // padded LDS row (floats): 112 B, 16B-aligned, bank-staggered

constexpr float R_C = 5.0f;
constexpr float SQ2 = 1.41421356237309515f;
constexpr float SQ3 = 1.73205080756887729f;
constexpr float SQ6 = 2.44948974968163702f;

// q[i][d][l] = sum_{j<k} g_ijd g_ikd P_l(cos th_jk)
//            = 0.5*scale_l * sum_{c in l} (sum_j g_jd F_c(u_j))^2 - 0.5*sum_j g_jd^2
// (Legendre addition theorem, traceless symmetric tensors; scale={1,1,3/2,5/2}).
// Latency-bound problem -> single-wave blocks, whole grid co-resident,
// barrier = waitcnt only, one coalesced b32 store per lane.
__global__ __launch_bounds__(64) void AngularDescriptor_kernel(
    const int*   __restrict__ types,
    const float* __restrict__ pos,
    const int*   __restrict__ nbr,
    const float* __restrict__ c_table,
    float*       __restrict__ out,
    int N)
{
    __shared__ float sF[APB][NCOMP][ROWP];   // [a][c][m], rows 112 B
    __shared__ float sg[APB][N_DESC][ROWP];  // [a][d][m], rows 112 B

    const int t     = threadIdx.x;
    const int atom0 = blockIdx.x * APB;

    // ---------------- phase 1: lanes 0..39 <-> (a, m) ----------------
    if (t < APB * M_NBR) {
        const int a    = (t >= M_NBR) ? 1 : 0;
        const int m    = t - a * M_NBR;
        const int atom = atom0 + a;
        if (atom < N) {
            const int j  = nbr[atom * M_NBR + m];
            const int ti = types[atom];
            const int tj = types[j];
            const float dx = pos[j * 3 + 0] - pos[atom * 3 + 0];
            const float dy = pos[j * 3 + 1] - pos[atom * 3 + 1];
            const float dz = pos[j * 3 + 2] - pos[atom * 3 + 2];
            const float r2   = dx * dx + dy * dy + dz * dz;
            const float rinv = __builtin_amdgcn_rsqf(r2);
            const float r    = r2 * rinv;

            // Chebyshev * 0.5*fc  (v_cos takes revolutions: pi*r/rc -> r/(2rc))
            const float fc  = (r < R_C)
                ? (0.5f * __builtin_amdgcn_cosf(r * (0.5f / R_C)) + 0.5f) : 0.0f;
            const float hfc = 0.5f * fc;
            const float u   = r * (1.0f / R_C) - 1.0f;
            const float x   = 2.0f * u * u - 1.0f;
            float ch[K_MAX];
            ch[0] = 2.0f * hfc;
            ch[1] = (x + 1.0f) * hfc;
            float tkm2 = 1.0f, tkm1 = x;
            #pragma unroll
            for (int k = 2; k < K_MAX; ++k) {
                const float tk = 2.0f * x * tkm1 - tkm2;
                ch[k] = (tk + 1.0f) * hfc;
                tkm2 = tkm1; tkm1 = tk;
            }

            // all 8 g_d inline; c row = 256 contiguous B of the L1-hot 4 KB table
            const float* crow = c_table + (ti * N_TYPES + tj) * (N_DESC * K_MAX);
            #pragma unroll
            for (int d = 0; d < N_DESC; ++d) {
                const float4 c0 = ((const float4*)crow)[2 * d + 0];
                const float4 c1 = ((const float4*)crow)[2 * d + 1];
                sg[a][d][m] = c0.x * ch[0] + c0.y * ch[1] + c0.z * ch[2] + c0.w * ch[3]
                            + c1.x * ch[4] + c1.y * ch[5] + c1.z * ch[6] + c1.w * ch[7];
            }

            // unit vector + tensor features
            const float ux = dx * rinv, uy = dy * rinv, uz = dz * rinv;
            const float x2 = ux * ux, y2 = uy * uy, z2 = uz * uz;
            float F[NCOMP];
            F[0]  = 1.0f;                       // l=0
            F[1]  = ux;  F[2] = uy;  F[3] = uz; // l=1
            F[4]  = x2 - (1.0f / 3.0f);         // l=2 (scale 3/2)
            F[5]  = y2 - (1.0f / 3.0f);
            F[6]  = z2 - (1.0f / 3.0f);
            F[7]  = SQ2 * ux * uy;
            F[8]  = SQ2 * ux * uz;
            F[9]  = SQ2 * uy * uz;
            F[10] = ux * (x2 - 0.6f);           // l=3 (scale 5/2)
            F[11] = uy * (y2 - 0.6f);
            F[12] = uz * (z2 - 0.6f);
            F[13] = SQ3 * uy * (x2 - 0.2f);
            F[14] = SQ3 * uz * (x2 - 0.2f);
            F[15] = SQ3 * ux * (y2 - 0.2f);
            F[16] = SQ3 * uz * (y2 - 0.2f);
            F[17] = SQ3 * ux * (z2 - 0.2f);
            F[18] = SQ3 * uy * (z2 - 0.2f);
            F[19] = SQ6 * ux * uy * uz;
            #pragma unroll
            for (int c = 0; c < NCOMP; ++c) sF[a][c][m] = F[c];
        }
    }
    __syncthreads();   // single-wave block: lowers to a waitcnt, no s_barrier

    // ---------------- phase 2: all 64 lanes <-> (a, d, q) ----------------
    {
        const int a    = t >> 5;
        const int d    = (t >> 2) & 7;
        const int q    = t & 3;
        const int atom = atom0 + a;
        if (atom < N) {
            const float4* gr = (const float4*)&sg[a][d][0];
            const float4 g0 = gr[0], g1 = gr[1], g2 = gr[2], g3 = gr[3], g4 = gr[4];
            float G2 = g0.x*g0.x + g0.y*g0.y + g0.z*g0.z + g0.w*g0.w
                     + g1.x*g1.x + g1.y*g1.y + g1.z*g1.z + g1.w*g1.w
                     + g2.x*g2.x + g2.y*g2.y + g2.z*g2.z + g2.w*g2.w
                     + g3.x*g3.x + g3.y*g3.y + g3.z*g3.z + g3.w*g3.w
                     + g4.x*g4.x + g4.y*g4.y + g4.z*g4.z + g4.w*g4.w;

            // A[i] for comps c = 4i + q (stride-4 assignment keeps l uniform-ish per i
            // and makes the 4 q-lanes' sF rows land on all 32 banks exactly once)
            float A[5];
            #pragma unroll
            for (int i = 0; i < 5; ++i) {
                const int c = 4 * i + q;
                const float4* Fr = (const float4*)&sF[a][c][0];
                const float4 f0 = Fr[0], f1 = Fr[1], f2 = Fr[2], f3 = Fr[3], f4 = Fr[4];
                A[i] = g0.x*f0.x + g0.y*f0.y + g0.z*f0.z + g0.w*f0.w
                     + g1.x*f1.x + g1.y*f1.y + g1.z*f1.z + g1.w*f1.w
                     + g2.x*f2.x + g2.y*f2.y + g2.z*f2.z + g2.w*f2.w
                     + g3.x*f3.x + g3.y*f3.y + g3.z*f3.z + g3.w*f3.w
                     + g4.x*f4.x + g4.y*f4.y + g4.z*f4.z + g4.w*f4.w;
            }

            // weighted squares into per-l partials
            float Px = 0.f, Py = 0.f, Pz = 0.f, Pw = 0.f;
            {   // i=0: c=q: q==0 -> l0 else l1 (both weight 0.5)
                const float v = 0.5f * A[0] * A[0];
                if (q == 0) Px = v; else Py = v;
            }
            Pz += 0.75f * A[1] * A[1];          // c=4+q  -> l2
            {   // i=2: c=8+q: q<2 -> l2 (c8,9), else l3 (c10,11)
                const float v = A[2] * A[2];
                if (q < 2) Pz += 0.75f * v; else Pw += 1.25f * v;
            }
            Pw += 1.25f * A[3] * A[3];          // c=12+q -> l3
            Pw += 1.25f * A[4] * A[4];          // c=16+q -> l3

            // sum the 4 q-lanes (xor 1, 2 stays inside the 4-lane (a,d) group)
            #pragma unroll
            for (int off = 1; off <= 2; off <<= 1) {
                Px += __shfl_xor(Px, off, 64);
                Py += __shfl_xor(Py, off, 64);
                Pz += __shfl_xor(Pz, off, 64);
                Pw += __shfl_xor(Pw, off, 64);
            }

            // lane q writes l=q component: out[(atom0+a)*32 + d*4 + q] == out[atom0*32 + t]
            const float v01 = (q & 1) ? Py : Px;
            const float v23 = (q & 1) ? Pw : Pz;
            out[atom0 * 32 + t] = ((q & 2) ? v23 : v01) - 0.5f * G2;
        }
    }
}

extern "C" void kernel_launch(void* const* d_in, const int* in_sizes, int n_in,
                              void* d_out, int out_size, void* d_ws, size_t ws_size,
                              hipStream_t stream) {
    const int*   types   = (const int*)  d_in[0];
    const float* pos     = (const float*)d_in[1];
    const int*   nbr     = (const int*)  d_in[2];
    const float* c_table = (const float*)d_in[3];
    float*       out     = (float*)      d_out;

    const int N = in_sizes[0];
    const int grid = (N + APB - 1) / APB;   // 5000 single-wave blocks, all co-resident
    AngularDescriptor_kernel<<<grid, 64, 0, stream>>>(types, pos, nbr, c_table, out, N);
}